// Round 19
// baseline (1219.758 us; speedup 1.0000x reference)
//
#include <hip/hip_runtime.h>
#include <hip/hip_bf16.h>

#define Tn 64
#define NB 8
#define NTH 512

typedef unsigned int u32;
typedef _Float16 h2 __attribute__((ext_vector_type(2)));
typedef __fp16 fp16x2 __attribute__((ext_vector_type(2)));
typedef short s16x8 __attribute__((ext_vector_type(8)));
typedef float f32x4 __attribute__((ext_vector_type(4)));
typedef float f32x2 __attribute__((ext_vector_type(2)));

#define MFMA16(a, b, c) __builtin_amdgcn_mfma_f32_16x16x32_bf16(a, b, c, 0, 0, 0)

__device__ __forceinline__ h2 as_h2(u32 u) { union { u32 u; h2 h; } c; c.u = u; return c.h; }

__device__ __forceinline__ u32 pkh(float a, float b) {
  union { u32 u; fp16x2 h; } c;
  c.h = __builtin_amdgcn_cvt_pkrtz(a, b);
  return c.u;
}

__device__ __forceinline__ unsigned short bfq(float x) {
  u32 u = __float_as_uint(x);
  return (unsigned short)((u + 0x7fffu + ((u >> 16) & 1)) >> 16);
}

__device__ __forceinline__ u32 pack2bf(float a, float b) {
  u32 ua = __float_as_uint(a), ub = __float_as_uint(b);
  ua = (ua + 0x7fffu + ((ua >> 16) & 1)) >> 16;
  ub = (ub + 0x7fffu + ((ub >> 16) & 1)) >> 16;
  return (ua & 0xffffu) | (ub << 16);
}

__device__ __forceinline__ s16x8 as_s16x8_u(u32 a, u32 b, u32 c2, u32 d) {
  union { u32 u[4]; s16x8 s; } cv;
  cv.u[0] = a; cv.u[1] = b; cv.u[2] = c2; cv.u[3] = d;
  return cv.s;
}

// ---- fp8 (OCP e4m3) pack/unpack ----
#if __has_builtin(__builtin_amdgcn_cvt_pk_fp8_f32) && __has_builtin(__builtin_amdgcn_cvt_pk_f32_fp8)
__device__ __forceinline__ u32 pk_fp8x4(float e0, float e1, float e2, float e3) {
  int w = __builtin_amdgcn_cvt_pk_fp8_f32(e0, e1, 0, false);
  w = __builtin_amdgcn_cvt_pk_fp8_f32(e2, e3, w, true);
  return (u32)w;
}
__device__ __forceinline__ f32x2 unpk_fp8lo(u32 w) {
  return __builtin_amdgcn_cvt_pk_f32_fp8((int)w, false);
}
__device__ __forceinline__ f32x2 unpk_fp8hi(u32 w) {
  return __builtin_amdgcn_cvt_pk_f32_fp8((int)w, true);
}
#else
__device__ __forceinline__ u32 fp8_1(float v) {
  if (!(v >= 0.015625f)) return 0u;
  u32 u = __float_as_uint(fminf(v, 448.f));
  int e8 = ((int)((u >> 23) & 0xff)) - 127 + 7;
  u32 m8 = (u >> 20) & 7, rnd = (u >> 19) & 1;
  u32 r = ((u32)e8 << 3) | m8;
  r += rnd;
  return r & 0xff;
}
__device__ __forceinline__ u32 pk_fp8x4(float e0, float e1, float e2, float e3) {
  return fp8_1(e0) | (fp8_1(e1) << 8) | (fp8_1(e2) << 16) | (fp8_1(e3) << 24);
}
__device__ __forceinline__ float fp8_dec(u32 b) {
  b &= 0xff;
  if (b == 0) return 0.f;
  u32 e = (b >> 3) & 0xf, m = b & 7;
  return __uint_as_float(((e + 127 - 7) << 23) | (m << 20));
}
__device__ __forceinline__ f32x2 unpk_fp8lo(u32 w) {
  f32x2 r; r.x = fp8_dec(w); r.y = fp8_dec(w >> 8); return r;
}
__device__ __forceinline__ f32x2 unpk_fp8hi(u32 w) {
  f32x2 r; r.x = fp8_dec(w >> 16); r.y = fp8_dec(w >> 24); return r;
}
#endif

#define FEXP(x) __builtin_amdgcn_exp2f(x)
#define CE 2.885390081777927f /* 2*log2(e) */
#define EC(v) fminf(FEXP(CE * (v)), 448.f)

__device__ __forceinline__ float fast_rcp(float x) { return __builtin_amdgcn_rcpf(x); }
__device__ __forceinline__ float fast_tanh(float x) {
  float e = __expf(2.f * x);
  return 1.f - 2.f * fast_rcp(1.f + e);
}
__device__ __forceinline__ float fast_sig(float x) {
  return fast_rcp(1.f + __expf(-x));
}

// ---------------- weight pre-pack (same layouts as R17/R18) ----------------
__global__ void pack_weights(const float* __restrict__ W_d_w,
                             const float* __restrict__ W_hh,
                             const float* __restrict__ W_dec_w,
                             const float* __restrict__ W_y_w,
                             const float* __restrict__ U_d_w,
                             short* __restrict__ WdP, short* __restrict__ WhhP,
                             short* __restrict__ WdecP, short* __restrict__ UdMP,
                             u32* __restrict__ WyP2) {
  const int i0 = blockIdx.x * blockDim.x + threadIdx.x;
  const int stride = gridDim.x * blockDim.x;
  for (int i = i0; i < 32768; i += stride) {  // WdP
    int e = i & 7, lane = (i >> 3) & 63, w = (i >> 9) & 7, kk = i >> 12;
    int n = w * 16 + (lane & 15), k = kk * 32 + (lane >> 4) * 8 + e;
    WdP[i] = (short)bfq(W_d_w[n * 256 + k]);
  }
  for (int i = i0; i < 65536; i += stride) {  // WhhP
    int e = i & 7, lane = (i >> 3) & 63, nt = (i >> 9) & 31, kk = i >> 14;
    int n = nt * 16 + (lane & 15), k = kk * 32 + (lane >> 4) * 8 + e;
    WhhP[i] = (short)bfq(W_hh[n * 128 + k]);
  }
  for (int i = i0; i < 1064960; i += stride) {  // WdecP (blocks 0..64)
    int e = i & 7, lane = (i >> 3) & 63, w = (i >> 9) & 7, kk = (i >> 12) & 3, tt = i >> 14;
    int n = w * 16 + (lane & 15), k = kk * 32 + (lane >> 4) * 8 + e;
    WdecP[i] = (short)bfq(W_dec_w[n * 8320 + tt * 128 + k]);
  }
  for (int i = i0; i < 16384; i += stride) {  // UdMP (A-frags, rows = m)
    int e = i & 7, lane = (i >> 3) & 63, kk = (i >> 9) & 3, mt = i >> 11;
    int m = mt * 16 + (lane & 15), k = kk * 32 + (lane >> 4) * 8 + e;
    UdMP[i] = (short)bfq(U_d_w[m * 128 + k]);
  }
  for (int i = i0; i < 16384; i += stride) {  // WyP2
    int jj = i & 63, k = i >> 6;
    WyP2[i] = pkh(W_y_w[(2 * jj) * 256 + k], W_y_w[(2 * jj + 1) * 256 + k]);
  }
}

// ---------------- fused scan, 2 blocks/CU ----------------
// LDS (bytes), STATIC (81024 <= 81920 -> 2 blocks/CU):
//   E     u32 [q<32][r<8][l<64]  @ 0      (65536)  4 fp8 E-values per u32
//   cat   u32 [1184]             @ 65536  (4736)   8 rows stride 132
//   x1h   f16 [8][128]           @ 70272  (2048)   X = exp2(CE*x1)
//   gth   f16 [8][512]           @ 72320  (8192)   gates (ew_s transient)
//   va2   f32 [128]              @ 80512  (512)
//   ---- epilogue aliases (E dead): beta @ 0 (2048), cat2 @ 4096 (8192)
#define LDS_BYTES 81024

// logit group: 8 m-values; E from fp8 LDS, X f16, va f32
#define QGROUP(G)                                                              \
  {                                                                            \
    u32 w0 = E[(2 * (G)) * 512 + wv * 64 + lane];                              \
    u32 w1 = E[(2 * (G) + 1) * 512 + wv * 64 + lane];                          \
    const u32* xp = (const u32*)(x1h + wv * 128 + (G) * 8);                    \
    u32 X0 = xp[0], X1 = xp[1], X2 = xp[2], X3 = xp[3];                        \
    float4 va = *(const float4*)(va2 + (G) * 8);                               \
    float4 vb = *(const float4*)(va2 + (G) * 8 + 4);                           \
    f32x2 e01 = unpk_fp8lo(w0), e23 = unpk_fp8hi(w0);                          \
    f32x2 e45 = unpk_fp8lo(w1), e67 = unpk_fp8hi(w1);                          \
    h2 x;                                                                      \
    x = as_h2(X0);                                                             \
    q0 = fmaf(va.x, fast_rcp(fmaf(e01.x, (float)x.x, 1.f)), q0);               \
    q1 = fmaf(va.y, fast_rcp(fmaf(e01.y, (float)x.y, 1.f)), q1);               \
    x = as_h2(X1);                                                             \
    q2 = fmaf(va.z, fast_rcp(fmaf(e23.x, (float)x.x, 1.f)), q2);               \
    q3 = fmaf(va.w, fast_rcp(fmaf(e23.y, (float)x.y, 1.f)), q3);               \
    x = as_h2(X2);                                                             \
    q0 = fmaf(vb.x, fast_rcp(fmaf(e45.x, (float)x.x, 1.f)), q0);               \
    q1 = fmaf(vb.y, fast_rcp(fmaf(e45.y, (float)x.y, 1.f)), q1);               \
    x = as_h2(X3);                                                             \
    q2 = fmaf(vb.z, fast_rcp(fmaf(e67.x, (float)x.x, 1.f)), q2);               \
    q3 = fmaf(vb.w, fast_rcp(fmaf(e67.y, (float)x.y, 1.f)), q3);               \
  }

#define AFRAG(KK) (*(const s16x8*)(cat_u + arow + (KK) * 16))

__global__ __launch_bounds__(NTH)
__attribute__((amdgpu_waves_per_eu(4, 4)))
void fused_main(
    const float* __restrict__ enc, const float* __restrict__ y,
    const float* __restrict__ W_d_b, const float* __restrict__ v_d_w,
    const float* __restrict__ w_tilda_w, const float* __restrict__ w_tilda_b,
    const float* __restrict__ W_ih, const float* __restrict__ b_ih,
    const float* __restrict__ b_hh, const float* __restrict__ W_dec_b,
    const float* __restrict__ W_y_b, const float* __restrict__ v_y_w,
    const float* __restrict__ v_y_b,
    const short* __restrict__ WdP, const short* __restrict__ WhhP,
    const short* __restrict__ WdecP, const short* __restrict__ UdMP,
    const u32* __restrict__ WyP2, float* __restrict__ out) {
  __shared__ char lds[LDS_BYTES];
  u32* E = (u32*)lds;
  u32* cat_u = (u32*)(lds + 65536);
  _Float16* x1h = (_Float16*)(lds + 70272);
  _Float16* gth = (_Float16*)(lds + 72320);
  float* va2 = (float*)(lds + 80512);
  float* beta_s = (float*)lds;           // epilogue alias (E dead)
  float* cat2 = (float*)(lds + 4096);    // epilogue alias (E dead)
  float* ew_s = (float*)gth;             // phase-0 transient (pre-t-loop)

  const int tid = threadIdx.x;
  const int lane = tid & 63;
  const int wv = tid >> 6;   // 0..7 == batch row
  const int b = blockIdx.x * NB + wv;
  const int j = lane;
  const int ccol = lane & 15;
  const int crow = (lane >> 4) * 4;

  // volatile views defeat LICM: these stay transient L1-hit loads, not regs
  volatile const float* vW_ih = W_ih;
  volatile const float* vb_ih = b_ih;
  volatile const float* vb_hh = b_hh;

  for (int i = tid; i < 1184; i += NTH) cat_u[i] = 0u;
  if (wv == 0) {
    va2[lane] = 2.f * v_d_w[lane];
    va2[64 + lane] = 2.f * v_d_w[64 + lane];
  }

  // ---- phase 0: y1 via MFMA (enc read ONCE), E (fp8) -> LDS; ew ----
  {
    const float* encb = enc + (size_t)b * (64 * 128);
    const int kbase = (lane >> 4) * 8;
#pragma unroll 1
    for (int lt = 0; lt < 4; ++lt) {
      const int l = lt * 16 + ccol;
      const float* rowp = encb + l * 128 + kbase;
      float ewp = 0.f;
      s16x8 B0, B1, B2, B3;
#define LOADB(KK, BV)                                                          \
      {                                                                        \
        float4 f0 = *(const float4*)(rowp + (KK) * 32);                        \
        float4 f1 = *(const float4*)(rowp + (KK) * 32 + 4);                    \
        BV = as_s16x8_u(pack2bf(f0.x, f0.y), pack2bf(f0.z, f0.w),              \
                        pack2bf(f1.x, f1.y), pack2bf(f1.z, f1.w));             \
        float4 w0v = *(const float4*)(w_tilda_w + (KK) * 32 + kbase);          \
        float4 w1v = *(const float4*)(w_tilda_w + (KK) * 32 + kbase + 4);      \
        ewp += f0.x * w0v.x + f0.y * w0v.y + f0.z * w0v.z + f0.w * w0v.w;      \
        ewp += f1.x * w1v.x + f1.y * w1v.y + f1.z * w1v.z + f1.w * w1v.w;      \
      }
      LOADB(0, B0) LOADB(1, B1) LOADB(2, B2) LOADB(3, B3)
#undef LOADB
      ewp += __shfl_xor(ewp, 16, 64);
      ewp += __shfl_xor(ewp, 32, 64);
      if (lane < 16) ew_s[wv * 64 + l] = ewp;
#pragma unroll
      for (int mt = 0; mt < 8; ++mt) {
        f32x4 c = {0.f, 0.f, 0.f, 0.f};
        c = MFMA16(*(const s16x8*)(UdMP + ((mt * 4 + 0) * 64 + lane) * 8), B0, c);
        c = MFMA16(*(const s16x8*)(UdMP + ((mt * 4 + 1) * 64 + lane) * 8), B1, c);
        c = MFMA16(*(const s16x8*)(UdMP + ((mt * 4 + 2) * 64 + lane) * 8), B2, c);
        c = MFMA16(*(const s16x8*)(UdMP + ((mt * 4 + 3) * 64 + lane) * 8), B3, c);
        const int q = mt * 4 + (lane >> 4);
        E[q * 512 + wv * 64 + lt * 16 + ccol] =
            pk_fp8x4(EC(c[0]), EC(c[1]), EC(c[2]), EC(c[3]));
      }
    }
  }
  __syncthreads();
  const float ew = ew_s[wv * 64 + lane];
  __syncthreads();

  const float wt_y = w_tilda_w[128];
  const float wt_b0 = w_tilda_b[0];
  float svv = v_d_w[lane] + v_d_w[64 + lane];
#pragma unroll
  for (int off = 32; off; off >>= 1) svv += __shfl_xor(svv, off, 64);
  const float sv = __int_as_float(__builtin_amdgcn_readfirstlane(__float_as_int(svv)));

  const int arow = ccol * 132 + (lane >> 4) * 4;  // rows>=8 read garbage: C rows discarded
  const float wdb_n = W_d_b[wv * 16 + ccol];
  const float dfb_n = W_dec_b[wv * 16 + ccol];
  f32x4 dfacc = {dfb_n, dfb_n, dfb_n, dfb_n};
  float s0 = 0.f, s1 = 0.f, beta_sv = 0.f;

#pragma unroll 1
  for (int t = 0; t < Tn; ++t) {
    // ---- phase A: GEMMs on matrix pipe (8 waves, 28 MFMA each) ----
    {
      f32x4 c1 = {wdb_n, wdb_n, wdb_n, wdb_n};
#pragma unroll
      for (int kk = 0; kk < 8; ++kk) {
        s16x8 bf = *(const s16x8*)(WdP + (((kk * 8 + wv) * 64 + lane) * 8));
        c1 = MFMA16(AFRAG(kk), bf, c1);
      }
      if (crow < 8) {
#pragma unroll
        for (int r4 = 0; r4 < 4; ++r4)
          x1h[(crow + r4) * 128 + wv * 16 + ccol] = (_Float16)FEXP(c1[r4] * CE);
      }
    }
    {
#pragma unroll
      for (int kk = 0; kk < 4; ++kk) {
        s16x8 bf = *(const s16x8*)(WdecP + ((((t * 4 + kk) * 8 + wv) * 64 + lane) * 8));
        dfacc = MFMA16(AFRAG(kk), bf, dfacc);
      }
    }
#pragma unroll
    for (int it = 0; it < 4; ++it) {
      const int nt = wv * 4 + it;
      const float bi = vb_ih[nt * 16 + ccol] + vb_hh[nt * 16 + ccol];  // L1-hot, transient
      f32x4 c2 = {bi, bi, bi, bi};
#pragma unroll
      for (int kk = 0; kk < 4; ++kk) {
        s16x8 bf = *(const s16x8*)(WhhP + (((kk * 32 + nt) * 64 + lane) * 8));
        c2 = MFMA16(AFRAG(kk), bf, c2);
      }
      if (crow < 8) {
#pragma unroll
        for (int r4 = 0; r4 < 4; ++r4)
          gth[(crow + r4) * 512 + nt * 16 + ccol] = (_Float16)c2[r4];
      }
    }
    __syncthreads();

    // ---- phase B: full logits for own row (fp8 E from LDS) ----
    float q0 = 0.f, q1 = 0.f, q2 = 0.f, q3 = 0.f;
    QGROUP(0)  QGROUP(1)  QGROUP(2)  QGROUP(3)
    QGROUP(4)  QGROUP(5)  QGROUP(6)  QGROUP(7)
    QGROUP(8)  QGROUP(9)  QGROUP(10) QGROUP(11)
    QGROUP(12) QGROUP(13) QGROUP(14) QGROUP(15)
    float lg = sv - (q0 + q1 + q2 + q3);
    float pexp = __expf(lg);  // |lg| bounded ~15: no max pass needed
    float smv = pexp, yt = pexp * ew;
#pragma unroll
    for (int off = 32; off; off >>= 1) {
      smv += __shfl_xor(smv, off, 64);
      yt += __shfl_xor(yt, off, 64);
    }
    float rs = fast_rcp(smv);
    if (t == Tn - 1) beta_sv = pexp * rs;
    float ytil = yt * rs + y[(size_t)b * 64 + t] * wt_y + wt_b0;

    const u32* gp = (const u32*)(gth + wv * 512 + 2 * j);
    h2 pgi = as_h2(gp[0]);
    h2 pgf = as_h2(gp[64]);
    h2 pgg = as_h2(gp[128]);
    h2 pgo = as_h2(gp[192]);
    // W_ih via volatile L1-hot loads (transient, not persistent regs)
    float i0 = fast_sig((float)pgi.x + ytil * vW_ih[2 * j]);
    float i1 = fast_sig((float)pgi.y + ytil * vW_ih[2 * j + 1]);
    float f0 = fast_sig((float)pgf.x + ytil * vW_ih[128 + 2 * j]);
    float f1 = fast_sig((float)pgf.y + ytil * vW_ih[128 + 2 * j + 1]);
    float g0 = fast_tanh((float)pgg.x + ytil * vW_ih[256 + 2 * j]);
    float g1 = fast_tanh((float)pgg.y + ytil * vW_ih[256 + 2 * j + 1]);
    float o0 = fast_sig((float)pgo.x + ytil * vW_ih[384 + 2 * j]);
    float o1 = fast_sig((float)pgo.y + ytil * vW_ih[384 + 2 * j + 1]);
    s0 = f0 * s0 + i0 * g0;
    s1 = f1 * s1 + i1 * g1;
    float d0 = o0 * fast_tanh(s0);
    float d1 = o1 * fast_tanh(s1);
    cat_u[wv * 132 + j] = pack2bf(d0, d1);
    cat_u[wv * 132 + 64 + j] = pack2bf(s0, s1);
    __syncthreads();
  }

  // ---- epilogue (E dead; beta/cat2 alias it) ----
  beta_s[wv * 64 + lane] = beta_sv;
  {
#pragma unroll
    for (int kk = 0; kk < 4; ++kk) {
      s16x8 bf = *(const s16x8*)(WdecP + ((((64 * 4 + kk) * 8 + wv) * 64 + lane) * 8));
      dfacc = MFMA16(AFRAG(kk), bf, dfacc);
    }
    if (crow < 8) {
#pragma unroll
      for (int r4 = 0; r4 < 4; ++r4)
        cat2[(crow + r4) * 256 + wv * 16 + ccol] = dfacc[r4];
    }
  }
  __syncthreads();

  // c_T for own row
  float c0 = 0.f, c1v = 0.f;
#pragma unroll 2
  for (int it = 0; it < 16; ++it) {
    float4 bv = *(const float4*)(beta_s + wv * 64 + it * 4);
    float2 e0 = *(const float2*)(enc + ((size_t)b * 64 + it * 4 + 0) * 128 + 2 * j);
    float2 e1 = *(const float2*)(enc + ((size_t)b * 64 + it * 4 + 1) * 128 + 2 * j);
    float2 e2 = *(const float2*)(enc + ((size_t)b * 64 + it * 4 + 2) * 128 + 2 * j);
    float2 e3 = *(const float2*)(enc + ((size_t)b * 64 + it * 4 + 3) * 128 + 2 * j);
    c0 = fmaf(bv.x, e0.x, c0); c1v = fmaf(bv.x, e0.y, c1v);
    c0 = fmaf(bv.y, e1.x, c0); c1v = fmaf(bv.y, e1.y, c1v);
    c0 = fmaf(bv.z, e2.x, c0); c1v = fmaf(bv.z, e2.y, c1v);
    c0 = fmaf(bv.w, e3.x, c0); c1v = fmaf(bv.w, e3.y, c1v);
  }
  *(float2*)(cat2 + wv * 256 + 128 + 2 * j) = make_float2(c0, c1v);

  // final head for own row
  float2 hb = *(const float2*)(W_y_b + 2 * j);
  float h0v = hb.x, h1v = hb.y;
  __syncthreads();
#pragma unroll 4
  for (int it = 0; it < 64; ++it) {
    float4 cv = *(const float4*)(cat2 + wv * 256 + it * 4);
    u32 w0 = WyP2[(it * 4 + 0) * 64 + j];
    u32 w1 = WyP2[(it * 4 + 1) * 64 + j];
    u32 w2 = WyP2[(it * 4 + 2) * 64 + j];
    u32 w3 = WyP2[(it * 4 + 3) * 64 + j];
    h2 p0 = as_h2(w0), p1 = as_h2(w1), p2 = as_h2(w2), p3 = as_h2(w3);
    h0v = fmaf(cv.x, (float)p0.x, h0v); h1v = fmaf(cv.x, (float)p0.y, h1v);
    h0v = fmaf(cv.y, (float)p1.x, h0v); h1v = fmaf(cv.y, (float)p1.y, h1v);
    h0v = fmaf(cv.z, (float)p2.x, h0v); h1v = fmaf(cv.z, (float)p2.y, h1v);
    h0v = fmaf(cv.w, (float)p3.x, h0v); h1v = fmaf(cv.w, (float)p3.y, h1v);
  }
  float2 vy = *(const float2*)(v_y_w + 2 * j);
  float rsum = h0v * vy.x + h1v * vy.y;
#pragma unroll
  for (int off = 32; off; off >>= 1) rsum += __shfl_xor(rsum, off, 64);
  if (lane == 0) out[b] = rsum + v_y_b[0];
}

extern "C" void kernel_launch(void* const* d_in, const int* in_sizes, int n_in,
                              void* d_out, int out_size, void* d_ws, size_t ws_size,
                              hipStream_t stream) {
  const float* enc = (const float*)d_in[0];
  const float* y = (const float*)d_in[1];
  const float* W_d_w = (const float*)d_in[2];
  const float* W_d_b = (const float*)d_in[3];
  const float* U_d_w = (const float*)d_in[4];
  const float* v_d_w = (const float*)d_in[5];
  const float* w_tilda_w = (const float*)d_in[6];
  const float* w_tilda_b = (const float*)d_in[7];
  const float* W_ih = (const float*)d_in[8];
  const float* b_ih = (const float*)d_in[9];
  const float* W_hh = (const float*)d_in[10];
  const float* b_hh = (const float*)d_in[11];
  const float* W_dec_w = (const float*)d_in[12];
  const float* W_dec_b = (const float*)d_in[13];
  const float* W_y_w = (const float*)d_in[14];
  const float* W_y_b = (const float*)d_in[15];
  const float* v_y_w = (const float*)d_in[16];
  const float* v_y_b = (const float*)d_in[17];

  char* ws = (char*)d_ws;
  short* WdP = (short*)(ws + 0);
  short* WhhP = (short*)(ws + 65536);
  short* WdecP = (short*)(ws + 196608);
  short* UdMP = (short*)(ws + 2326528);
  u32* WyP2 = (u32*)(ws + 2359552);

  pack_weights<<<512, 256, 0, stream>>>(W_d_w, W_hh, W_dec_w, W_y_w, U_d_w,
                                        WdP, WhhP, WdecP, UdMP, WyP2);
  fused_main<<<4096 / NB, NTH, 0, stream>>>(
      enc, y, W_d_b, v_d_w, w_tilda_w, w_tilda_b, W_ih, b_ih, b_hh, W_dec_b,
      W_y_b, v_y_w, v_y_b, WdP, WhhP, WdecP, UdMP, WyP2, (float*)d_out);
}

// Round 20
// 624.588 us; speedup vs baseline: 1.9529x; 1.9529x over previous
//
#include <hip/hip_runtime.h>
#include <hip/hip_bf16.h>

#define Tn 64
#define NB 16
#define NTH 1024

typedef unsigned int u32;
typedef _Float16 h2 __attribute__((ext_vector_type(2)));
typedef __fp16 fp16x2 __attribute__((ext_vector_type(2)));
typedef short s16x8 __attribute__((ext_vector_type(8)));
typedef float f32x4 __attribute__((ext_vector_type(4)));
typedef float f32x2 __attribute__((ext_vector_type(2)));

#define MFMA16(a, b, c) __builtin_amdgcn_mfma_f32_16x16x32_bf16(a, b, c, 0, 0, 0)

__device__ __forceinline__ h2 as_h2(u32 u) { union { u32 u; h2 h; } c; c.u = u; return c.h; }

__device__ __forceinline__ u32 pkh(float a, float b) {
  union { u32 u; fp16x2 h; } c;
  c.h = __builtin_amdgcn_cvt_pkrtz(a, b);
  return c.u;
}

__device__ __forceinline__ unsigned short bfq(float x) {
  u32 u = __float_as_uint(x);
  return (unsigned short)((u + 0x7fffu + ((u >> 16) & 1)) >> 16);
}

__device__ __forceinline__ u32 pack2bf(float a, float b) {
  u32 ua = __float_as_uint(a), ub = __float_as_uint(b);
  ua = (ua + 0x7fffu + ((ua >> 16) & 1)) >> 16;
  ub = (ub + 0x7fffu + ((ub >> 16) & 1)) >> 16;
  return (ua & 0xffffu) | (ub << 16);
}

__device__ __forceinline__ s16x8 as_s16x8_u(u32 a, u32 b, u32 c2, u32 d) {
  union { u32 u[4]; s16x8 s; } cv;
  cv.u[0] = a; cv.u[1] = b; cv.u[2] = c2; cv.u[3] = d;
  return cv.s;
}

// ---- fp8 (OCP e4m3) pack/unpack ----
#if __has_builtin(__builtin_amdgcn_cvt_pk_fp8_f32) && __has_builtin(__builtin_amdgcn_cvt_pk_f32_fp8)
__device__ __forceinline__ u32 pk_fp8x4(float e0, float e1, float e2, float e3) {
  int w = __builtin_amdgcn_cvt_pk_fp8_f32(e0, e1, 0, false);
  w = __builtin_amdgcn_cvt_pk_fp8_f32(e2, e3, w, true);
  return (u32)w;
}
__device__ __forceinline__ f32x2 unpk_fp8lo(u32 w) {
  return __builtin_amdgcn_cvt_pk_f32_fp8((int)w, false);
}
__device__ __forceinline__ f32x2 unpk_fp8hi(u32 w) {
  return __builtin_amdgcn_cvt_pk_f32_fp8((int)w, true);
}
#else
__device__ __forceinline__ u32 fp8_1(float v) {
  if (!(v >= 0.015625f)) return 0u;
  u32 u = __float_as_uint(fminf(v, 448.f));
  int e8 = ((int)((u >> 23) & 0xff)) - 127 + 7;
  u32 m8 = (u >> 20) & 7, rnd = (u >> 19) & 1;
  u32 r = ((u32)e8 << 3) | m8;
  r += rnd;
  return r & 0xff;
}
__device__ __forceinline__ u32 pk_fp8x4(float e0, float e1, float e2, float e3) {
  return fp8_1(e0) | (fp8_1(e1) << 8) | (fp8_1(e2) << 16) | (fp8_1(e3) << 24);
}
__device__ __forceinline__ float fp8_dec(u32 b) {
  b &= 0xff;
  if (b == 0) return 0.f;
  u32 e = (b >> 3) & 0xf, m = b & 7;
  return __uint_as_float(((e + 127 - 7) << 23) | (m << 20));
}
__device__ __forceinline__ f32x2 unpk_fp8lo(u32 w) {
  f32x2 r; r.x = fp8_dec(w); r.y = fp8_dec(w >> 8); return r;
}
__device__ __forceinline__ f32x2 unpk_fp8hi(u32 w) {
  f32x2 r; r.x = fp8_dec(w >> 16); r.y = fp8_dec(w >> 24); return r;
}
#endif

#define FEXP(x) __builtin_amdgcn_exp2f(x)
#define CE 2.885390081777927f /* 2*log2(e) */
#define EC(v) fminf(FEXP(CE * (v)), 448.f)

__device__ __forceinline__ float fast_rcp(float x) { return __builtin_amdgcn_rcpf(x); }
__device__ __forceinline__ float fast_tanh(float x) {
  float e = __expf(2.f * x);
  return 1.f - 2.f * fast_rcp(1.f + e);
}
__device__ __forceinline__ float fast_sig(float x) {
  return fast_rcp(1.f + __expf(-x));
}

// ---------------- weight pre-pack (same layouts as R17) ----------------
__global__ void pack_weights(const float* __restrict__ W_d_w,
                             const float* __restrict__ W_hh,
                             const float* __restrict__ W_dec_w,
                             const float* __restrict__ W_y_w,
                             const float* __restrict__ U_d_w,
                             short* __restrict__ WdP, short* __restrict__ WhhP,
                             short* __restrict__ WdecP, short* __restrict__ UdMP,
                             u32* __restrict__ WyP2) {
  const int i0 = blockIdx.x * blockDim.x + threadIdx.x;
  const int stride = gridDim.x * blockDim.x;
  for (int i = i0; i < 32768; i += stride) {  // WdP
    int e = i & 7, lane = (i >> 3) & 63, w = (i >> 9) & 7, kk = i >> 12;
    int n = w * 16 + (lane & 15), k = kk * 32 + (lane >> 4) * 8 + e;
    WdP[i] = (short)bfq(W_d_w[n * 256 + k]);
  }
  for (int i = i0; i < 65536; i += stride) {  // WhhP
    int e = i & 7, lane = (i >> 3) & 63, nt = (i >> 9) & 31, kk = i >> 14;
    int n = nt * 16 + (lane & 15), k = kk * 32 + (lane >> 4) * 8 + e;
    WhhP[i] = (short)bfq(W_hh[n * 128 + k]);
  }
  for (int i = i0; i < 1064960; i += stride) {  // WdecP (blocks 0..64)
    int e = i & 7, lane = (i >> 3) & 63, w = (i >> 9) & 7, kk = (i >> 12) & 3, tt = i >> 14;
    int n = w * 16 + (lane & 15), k = kk * 32 + (lane >> 4) * 8 + e;
    WdecP[i] = (short)bfq(W_dec_w[n * 8320 + tt * 128 + k]);
  }
  for (int i = i0; i < 16384; i += stride) {  // UdMP (A-frags, rows = m)
    int e = i & 7, lane = (i >> 3) & 63, kk = (i >> 9) & 3, mt = i >> 11;
    int m = mt * 16 + (lane & 15), k = kk * 32 + (lane >> 4) * 8 + e;
    UdMP[i] = (short)bfq(U_d_w[m * 128 + k]);
  }
  for (int i = i0; i < 16384; i += stride) {  // WyP2
    int jj = i & 63, k = i >> 6;
    WyP2[i] = pkh(W_y_w[(2 * jj) * 256 + k], W_y_w[(2 * jj + 1) * 256 + k]);
  }
}

// ---------------- fused scan (R17 structure) ----------------
// LDS (bytes), STATIC:
//   E     u32 [q<32][r<16][l<64]  @ 0       (131072)  4 fp8 E-values per u32
//   cat   u32 [16][132]           @ 131072  (8448)
//   x1h   f16 [16][128]           @ 139520  (4096)    X = exp2(CE*x1)
//   gth   f16 [16][512]           @ 143616  (16384)   gates (ew_s transient)
//   va2   f32 [128]               @ 160000  (512)
//   wih_s f32 [512]               @ 160512  (2048)
//   ---- epilogue aliases (E dead): beta @ 0 (4096), cat2 @ 4096 (16384)
#define LDS_BYTES 162560

// logit group: 8 m-values via 4 PAIRED rcp (exact algebra):
// va*sig(A)+vb*sig(B) = [va(1+B)+vb(1+A)] * rcp[(1+A)(1+B)]
#define QPAIR(QACC, EE, XX, VA, VB)                                            \
  {                                                                            \
    float tA = fmaf((EE).x, (float)(XX).x, 1.f);                               \
    float tB = fmaf((EE).y, (float)(XX).y, 1.f);                               \
    float num = fmaf((VA), tB, (VB) * tA);                                     \
    QACC = fmaf(num, fast_rcp(tA * tB), QACC);                                 \
  }

#define QGROUP(G)                                                              \
  {                                                                            \
    u32 w0 = E[(2 * (G)) * 1024 + wv * 64 + lane];                             \
    u32 w1 = E[(2 * (G) + 1) * 1024 + wv * 64 + lane];                         \
    const u32* xp = (const u32*)(x1h + wv * 128 + (G) * 8);                    \
    u32 X0 = xp[0], X1 = xp[1], X2 = xp[2], X3 = xp[3];                        \
    float4 va = *(const float4*)(va2 + (G) * 8);                               \
    float4 vb = *(const float4*)(va2 + (G) * 8 + 4);                           \
    f32x2 e01 = unpk_fp8lo(w0), e23 = unpk_fp8hi(w0);                          \
    f32x2 e45 = unpk_fp8lo(w1), e67 = unpk_fp8hi(w1);                          \
    QPAIR(q0, e01, as_h2(X0), va.x, va.y)                                      \
    QPAIR(q1, e23, as_h2(X1), va.z, va.w)                                      \
    QPAIR(q2, e45, as_h2(X2), vb.x, vb.y)                                      \
    QPAIR(q3, e67, as_h2(X3), vb.z, vb.w)                                      \
  }

#define AFRAG(KK) (*(const s16x8*)(cat_u + arow + (KK) * 16))

__global__ __launch_bounds__(NTH)
__attribute__((amdgpu_waves_per_eu(4, 4)))
void fused_main(
    const float* __restrict__ enc, const float* __restrict__ y,
    const float* __restrict__ W_d_b, const float* __restrict__ v_d_w,
    const float* __restrict__ w_tilda_w, const float* __restrict__ w_tilda_b,
    const float* __restrict__ W_ih, const float* __restrict__ b_ih,
    const float* __restrict__ b_hh, const float* __restrict__ W_dec_b,
    const float* __restrict__ W_y_b, const float* __restrict__ v_y_w,
    const float* __restrict__ v_y_b,
    const short* __restrict__ WdP, const short* __restrict__ WhhP,
    const short* __restrict__ WdecP, const short* __restrict__ UdMP,
    const u32* __restrict__ WyP2, float* __restrict__ out) {
  __shared__ char lds[LDS_BYTES];
  u32* E = (u32*)lds;
  u32* cat_u = (u32*)(lds + 131072);
  _Float16* x1h = (_Float16*)(lds + 139520);
  _Float16* gth = (_Float16*)(lds + 143616);
  float* va2 = (float*)(lds + 160000);
  float* wih_s = (float*)(lds + 160512);
  float* beta_s = (float*)lds;           // epilogue alias (E dead)
  float* cat2 = (float*)(lds + 4096);    // epilogue alias (E dead)
  float* ew_s = (float*)gth;             // phase-0 transient (pre-t-loop)

  const int tid = threadIdx.x;
  const int lane = tid & 63;
  const int wv = tid >> 6;   // 0..15 == batch row
  const int b = blockIdx.x * NB + wv;
  const int j = lane;
  const int ccol = lane & 15;
  const int crow = (lane >> 4) * 4;

  for (int i = tid; i < 16 * 132; i += NTH) cat_u[i] = 0u;
  if (wv == 0) {
    va2[lane] = 2.f * v_d_w[lane];
    va2[64 + lane] = 2.f * v_d_w[64 + lane];
  }
  for (int i = tid; i < 512; i += NTH) wih_s[i] = W_ih[i];

  // ---- phase 0: y1 via MFMA (enc read ONCE), E (fp8) -> LDS; ew ----
  {
    const float* encb = enc + (size_t)b * (64 * 128);
    const int kbase = (lane >> 4) * 8;
#pragma unroll 1
    for (int lt = 0; lt < 4; ++lt) {
      const int l = lt * 16 + ccol;
      const float* rowp = encb + l * 128 + kbase;
      float ewp = 0.f;
      s16x8 B0, B1, B2, B3;
#define LOADB(KK, BV)                                                          \
      {                                                                        \
        float4 f0 = *(const float4*)(rowp + (KK) * 32);                        \
        float4 f1 = *(const float4*)(rowp + (KK) * 32 + 4);                    \
        BV = as_s16x8_u(pack2bf(f0.x, f0.y), pack2bf(f0.z, f0.w),              \
                        pack2bf(f1.x, f1.y), pack2bf(f1.z, f1.w));             \
        float4 w0v = *(const float4*)(w_tilda_w + (KK) * 32 + kbase);          \
        float4 w1v = *(const float4*)(w_tilda_w + (KK) * 32 + kbase + 4);      \
        ewp += f0.x * w0v.x + f0.y * w0v.y + f0.z * w0v.z + f0.w * w0v.w;      \
        ewp += f1.x * w1v.x + f1.y * w1v.y + f1.z * w1v.z + f1.w * w1v.w;      \
      }
      LOADB(0, B0) LOADB(1, B1) LOADB(2, B2) LOADB(3, B3)
#undef LOADB
      ewp += __shfl_xor(ewp, 16, 64);
      ewp += __shfl_xor(ewp, 32, 64);
      if (lane < 16) ew_s[wv * 64 + l] = ewp;
#pragma unroll
      for (int mt = 0; mt < 8; ++mt) {
        f32x4 c = {0.f, 0.f, 0.f, 0.f};
        c = MFMA16(*(const s16x8*)(UdMP + ((mt * 4 + 0) * 64 + lane) * 8), B0, c);
        c = MFMA16(*(const s16x8*)(UdMP + ((mt * 4 + 1) * 64 + lane) * 8), B1, c);
        c = MFMA16(*(const s16x8*)(UdMP + ((mt * 4 + 2) * 64 + lane) * 8), B2, c);
        c = MFMA16(*(const s16x8*)(UdMP + ((mt * 4 + 3) * 64 + lane) * 8), B3, c);
        const int q = mt * 4 + (lane >> 4);
        E[q * 1024 + wv * 64 + lt * 16 + ccol] =
            pk_fp8x4(EC(c[0]), EC(c[1]), EC(c[2]), EC(c[3]));
      }
    }
  }
  __syncthreads();
  const float ew = ew_s[wv * 64 + lane];
  __syncthreads();

  const float wt_y = w_tilda_w[128];
  const float wt_b0 = w_tilda_b[0];
  float svv = v_d_w[lane] + v_d_w[64 + lane];
#pragma unroll
  for (int off = 32; off; off >>= 1) svv += __shfl_xor(svv, off, 64);
  const float sv = __int_as_float(__builtin_amdgcn_readfirstlane(__float_as_int(svv)));

  const int arow = ccol * 132 + (lane >> 4) * 4;
  const float wdb_n = W_d_b[(wv & 7) * 16 + ccol];
  const float dfb_n = W_dec_b[(wv & 7) * 16 + ccol];
  const float bini0 = b_ih[wv * 32 + ccol] + b_hh[wv * 32 + ccol];
  const float bini1 = b_ih[wv * 32 + 16 + ccol] + b_hh[wv * 32 + 16 + ccol];
  f32x4 dfacc = {dfb_n, dfb_n, dfb_n, dfb_n};
  float s0 = 0.f, s1 = 0.f, beta_sv = 0.f;

#pragma unroll 1
  for (int t = 0; t < Tn; ++t) {
    // ---- phase A: GEMMs on matrix pipe ----
    if (wv < 8) {
      f32x4 c1 = {wdb_n, wdb_n, wdb_n, wdb_n};
#pragma unroll
      for (int kk = 0; kk < 8; ++kk) {
        s16x8 bf = *(const s16x8*)(WdP + (((kk * 8 + wv) * 64 + lane) * 8));
        c1 = MFMA16(AFRAG(kk), bf, c1);
      }
#pragma unroll
      for (int r4 = 0; r4 < 4; ++r4)
        x1h[(crow + r4) * 128 + wv * 16 + ccol] = (_Float16)FEXP(c1[r4] * CE);
    } else {
      const int w8 = wv - 8;
#pragma unroll
      for (int kk = 0; kk < 4; ++kk) {
        s16x8 bf = *(const s16x8*)(WdecP + ((((t * 4 + kk) * 8 + w8) * 64 + lane) * 8));
        dfacc = MFMA16(AFRAG(kk), bf, dfacc);
      }
    }
#pragma unroll
    for (int it = 0; it < 2; ++it) {
      const float bini = it ? bini1 : bini0;
      f32x4 c2 = {bini, bini, bini, bini};
      const int nt = wv * 2 + it;
#pragma unroll
      for (int kk = 0; kk < 4; ++kk) {
        s16x8 bf = *(const s16x8*)(WhhP + (((kk * 32 + nt) * 64 + lane) * 8));
        c2 = MFMA16(AFRAG(kk), bf, c2);
      }
#pragma unroll
      for (int r4 = 0; r4 < 4; ++r4)
        gth[(crow + r4) * 512 + nt * 16 + ccol] = (_Float16)c2[r4];
    }
    __syncthreads();

    // ---- phase B: full logits for own row (fp8 E, paired rcp) ----
    float q0 = 0.f, q1 = 0.f, q2 = 0.f, q3 = 0.f;
    QGROUP(0)  QGROUP(1)  QGROUP(2)  QGROUP(3)
    QGROUP(4)  QGROUP(5)  QGROUP(6)  QGROUP(7)
    QGROUP(8)  QGROUP(9)  QGROUP(10) QGROUP(11)
    QGROUP(12) QGROUP(13) QGROUP(14) QGROUP(15)
    float lg = sv - (q0 + q1 + q2 + q3);
    float pexp = __expf(lg);  // |lg| bounded ~15: no max pass needed
    float smv = pexp, yt = pexp * ew;
#pragma unroll
    for (int off = 32; off; off >>= 1) {
      smv += __shfl_xor(smv, off, 64);
      yt += __shfl_xor(yt, off, 64);
    }
    float rs = fast_rcp(smv);
    if (t == Tn - 1) beta_sv = pexp * rs;
    float ytil = yt * rs + y[(size_t)b * 64 + t] * wt_y + wt_b0;

    const u32* gp = (const u32*)(gth + wv * 512 + 2 * j);
    h2 pgi = as_h2(gp[0]);
    h2 pgf = as_h2(gp[64]);
    h2 pgg = as_h2(gp[128]);
    h2 pgo = as_h2(gp[192]);
    float2 wi0 = *(const float2*)(wih_s + 2 * j);
    float2 wi1 = *(const float2*)(wih_s + 128 + 2 * j);
    float2 wi2 = *(const float2*)(wih_s + 256 + 2 * j);
    float2 wi3 = *(const float2*)(wih_s + 384 + 2 * j);
    float i0 = fast_sig((float)pgi.x + ytil * wi0.x);
    float i1 = fast_sig((float)pgi.y + ytil * wi0.y);
    float f0 = fast_sig((float)pgf.x + ytil * wi1.x);
    float f1 = fast_sig((float)pgf.y + ytil * wi1.y);
    float g0 = fast_tanh((float)pgg.x + ytil * wi2.x);
    float g1 = fast_tanh((float)pgg.y + ytil * wi2.y);
    float o0 = fast_sig((float)pgo.x + ytil * wi3.x);
    float o1 = fast_sig((float)pgo.y + ytil * wi3.y);
    s0 = f0 * s0 + i0 * g0;
    s1 = f1 * s1 + i1 * g1;
    float d0 = o0 * fast_tanh(s0);
    float d1 = o1 * fast_tanh(s1);
    cat_u[wv * 132 + j] = pack2bf(d0, d1);
    cat_u[wv * 132 + 64 + j] = pack2bf(s0, s1);
    __syncthreads();
  }

  // ---- epilogue (E dead; beta/cat2 alias it) ----
  beta_s[wv * 64 + lane] = beta_sv;
  if (wv >= 8) {  // finish d_fin with Wdec block 64
    const int w8 = wv - 8;
#pragma unroll
    for (int kk = 0; kk < 4; ++kk) {
      s16x8 bf = *(const s16x8*)(WdecP + ((((64 * 4 + kk) * 8 + w8) * 64 + lane) * 8));
      dfacc = MFMA16(AFRAG(kk), bf, dfacc);
    }
#pragma unroll
    for (int r4 = 0; r4 < 4; ++r4)
      cat2[(crow + r4) * 256 + w8 * 16 + ccol] = dfacc[r4];
  }
  __syncthreads();

  // c_T for own row
  float c0 = 0.f, c1v = 0.f;
#pragma unroll 2
  for (int it = 0; it < 16; ++it) {
    float4 bv = *(const float4*)(beta_s + wv * 64 + it * 4);
    float2 e0 = *(const float2*)(enc + ((size_t)b * 64 + it * 4 + 0) * 128 + 2 * j);
    float2 e1 = *(const float2*)(enc + ((size_t)b * 64 + it * 4 + 1) * 128 + 2 * j);
    float2 e2 = *(const float2*)(enc + ((size_t)b * 64 + it * 4 + 2) * 128 + 2 * j);
    float2 e3 = *(const float2*)(enc + ((size_t)b * 64 + it * 4 + 3) * 128 + 2 * j);
    c0 = fmaf(bv.x, e0.x, c0); c1v = fmaf(bv.x, e0.y, c1v);
    c0 = fmaf(bv.y, e1.x, c0); c1v = fmaf(bv.y, e1.y, c1v);
    c0 = fmaf(bv.z, e2.x, c0); c1v = fmaf(bv.z, e2.y, c1v);
    c0 = fmaf(bv.w, e3.x, c0); c1v = fmaf(bv.w, e3.y, c1v);
  }
  *(float2*)(cat2 + wv * 256 + 128 + 2 * j) = make_float2(c0, c1v);

  // final head for own row
  float2 hb = *(const float2*)(W_y_b + 2 * j);
  float h0v = hb.x, h1v = hb.y;
  __syncthreads();
#pragma unroll 4
  for (int it = 0; it < 64; ++it) {
    float4 cv = *(const float4*)(cat2 + wv * 256 + it * 4);
    u32 w0 = WyP2[(it * 4 + 0) * 64 + j];
    u32 w1 = WyP2[(it * 4 + 1) * 64 + j];
    u32 w2 = WyP2[(it * 4 + 2) * 64 + j];
    u32 w3 = WyP2[(it * 4 + 3) * 64 + j];
    h2 p0 = as_h2(w0), p1 = as_h2(w1), p2 = as_h2(w2), p3 = as_h2(w3);
    h0v = fmaf(cv.x, (float)p0.x, h0v); h1v = fmaf(cv.x, (float)p0.y, h1v);
    h0v = fmaf(cv.y, (float)p1.x, h0v); h1v = fmaf(cv.y, (float)p1.y, h1v);
    h0v = fmaf(cv.z, (float)p2.x, h0v); h1v = fmaf(cv.z, (float)p2.y, h1v);
    h0v = fmaf(cv.w, (float)p3.x, h0v); h1v = fmaf(cv.w, (float)p3.y, h1v);
  }
  float2 vy = *(const float2*)(v_y_w + 2 * j);
  float rsum = h0v * vy.x + h1v * vy.y;
#pragma unroll
  for (int off = 32; off; off >>= 1) rsum += __shfl_xor(rsum, off, 64);
  if (lane == 0) out[b] = rsum + v_y_b[0];
}

extern "C" void kernel_launch(void* const* d_in, const int* in_sizes, int n_in,
                              void* d_out, int out_size, void* d_ws, size_t ws_size,
                              hipStream_t stream) {
  const float* enc = (const float*)d_in[0];
  const float* y = (const float*)d_in[1];
  const float* W_d_w = (const float*)d_in[2];
  const float* W_d_b = (const float*)d_in[3];
  const float* U_d_w = (const float*)d_in[4];
  const float* v_d_w = (const float*)d_in[5];
  const float* w_tilda_w = (const float*)d_in[6];
  const float* w_tilda_b = (const float*)d_in[7];
  const float* W_ih = (const float*)d_in[8];
  const float* b_ih = (const float*)d_in[9];
  const float* W_hh = (const float*)d_in[10];
  const float* b_hh = (const float*)d_in[11];
  const float* W_dec_w = (const float*)d_in[12];
  const float* W_dec_b = (const float*)d_in[13];
  const float* W_y_w = (const float*)d_in[14];
  const float* W_y_b = (const float*)d_in[15];
  const float* v_y_w = (const float*)d_in[16];
  const float* v_y_b = (const float*)d_in[17];

  char* ws = (char*)d_ws;
  short* WdP = (short*)(ws + 0);
  short* WhhP = (short*)(ws + 65536);
  short* WdecP = (short*)(ws + 196608);
  short* UdMP = (short*)(ws + 2326528);
  u32* WyP2 = (u32*)(ws + 2359552);

  pack_weights<<<512, 256, 0, stream>>>(W_d_w, W_hh, W_dec_w, W_y_w, U_d_w,
                                        WdP, WhhP, WdecP, UdMP, WyP2);
  fused_main<<<4096 / NB, NTH, 0, stream>>>(
      enc, y, W_d_b, v_d_w, w_tilda_w, w_tilda_b, W_ih, b_ih, b_hh, W_dec_b,
      W_y_b, v_y_w, v_y_b, WdP, WhhP, WdecP, UdMP, WyP2, (float*)d_out);
}